// Round 7
// baseline (196.588 us; speedup 1.0000x reference)
//
#include <hip/hip_runtime.h>

// Problem constants (from reference): B=8, H=16, T=16, D=128, S=4096
constexpr int B = 8;
constexpr int H = 16;
constexpr int T = 16;
constexpr int D = 128;
constexpr int S = 4096;
constexpr int D4 = D / 4;                              // float4 per row = 32
constexpr size_t CACHE_ELEMS = (size_t)B * H * S * D;  // 67,108,864 floats
constexpr size_t CACHE_F4    = CACHE_ELEMS / 4;        // 16,777,216 float4

// Native clang vector type — valid for __builtin_nontemporal_{load,store}.
typedef float f4 __attribute__((ext_vector_type(4)));

// Copy tuning: 2048 blocks x 256 threads; each half (k/v) gets 1024 blocks.
// UNROLL=8 (R5 best). NT on STORES only this round (A/B vs NT-both=188.6us):
// hypothesis is the R3->R5 win was write-allocate avoidance on the store
// stream; plain loads keep normal L2 read path.
constexpr int TPB = 256;
constexpr int COPY_BLOCKS = 2048;
constexpr int BLOCKS_PER_HALF = COPY_BLOCKS / 2;       // 1024
constexpr int UNROLL = 8;
constexpr int ITERS = 8;                                // 8*8 = 64 f4/thread
constexpr int F4_PER_BLOCK = TPB * UNROLL * ITERS;      // 16384 f4 = 512 rows
constexpr int ROWS_PER_BLOCK = F4_PER_BLOCK / D4;       // 512 (within one b,h)
// sanity: 1024 * 16384 = 16,777,216 = CACHE_F4; S/ROWS_PER_BLOCK = 8 blocks/(b,h)

__global__ void __launch_bounds__(TPB)
kv_fused_kernel(const f4* __restrict__ k_cache,
                const f4* __restrict__ v_cache,
                const f4* __restrict__ k_new,
                const f4* __restrict__ v_new,
                const int* __restrict__ input_pos,      // (B, T)
                f4* __restrict__ out) {
    int blk = blockIdx.x;
    const f4* __restrict__ src;
    const f4* __restrict__ newsrc;
    f4* __restrict__ dst;
    if (blk < BLOCKS_PER_HALF) {
        src = k_cache; newsrc = k_new; dst = out;
    } else {
        blk -= BLOCKS_PER_HALF;
        src = v_cache; newsrc = v_new; dst = out + CACHE_F4;
    }

    // ---- Prefetch scatter operands (hide the dependent-load tail) ----
    // Block covers (b,h) = blk/8, s in [s0, s0+512) with s0 = (blk%8)*512.
    int bh = blk >> 3;                // b*H + h
    int b  = bh >> 4;                 // H = 16
    int s0 = (blk & 7) * ROWS_PER_BLOCK;
    int d4 = threadIdx.x & (D4 - 1);  // 0..31
    int tl = threadIdx.x >> 5;        // 0..7
    int  p_pre[T / 8];
    f4   r_pre[T / 8];
#pragma unroll
    for (int tg = 0; tg < T / 8; ++tg) {
        int t = tg * 8 + tl;
        p_pre[tg] = input_pos[b * T + t];
        r_pre[tg] = newsrc[((size_t)bh * T + t) * D4 + d4];
    }

    // ---- Phase 1: bulk copy of this block's 512-row slice ----
    // Plain loads (cached), non-temporal stores (no write-allocate).
    size_t base = (size_t)blk * F4_PER_BLOCK + threadIdx.x;
    for (int it = 0; it < ITERS; ++it) {
        size_t a = base + (size_t)it * (TPB * UNROLL);
        f4 r[UNROLL];
#pragma unroll
        for (int u = 0; u < UNROLL; ++u)
            r[u] = src[a + (size_t)u * TPB];
#pragma unroll
        for (int u = 0; u < UNROLL; ++u)
            __builtin_nontemporal_store(r[u], &dst[a + (size_t)u * TPB]);
    }

    // ---- Phase 2: overwrite scattered rows that land in this block's slice ----
    __syncthreads();
#pragma unroll
    for (int tg = 0; tg < T / 8; ++tg) {
        int p = p_pre[tg];
        if (p >= s0 && p < s0 + ROWS_PER_BLOCK) {
            dst[((size_t)bh * S + p) * D4 + d4] = r_pre[tg];
        }
    }
}

extern "C" void kernel_launch(void* const* d_in, const int* in_sizes, int n_in,
                              void* d_out, int out_size, void* d_ws, size_t ws_size,
                              hipStream_t stream) {
    // setup_inputs order: input_pos, k, v, k_cache, v_cache
    const int* input_pos = (const int*)d_in[0];
    const f4*  k_new     = (const f4*)d_in[1];
    const f4*  v_new     = (const f4*)d_in[2];
    const f4*  k_cache   = (const f4*)d_in[3];
    const f4*  v_cache   = (const f4*)d_in[4];

    f4* out = (f4*)d_out;

    // Single fused dispatch: copy both caches + in-block scatter overwrite.
    kv_fused_kernel<<<COPY_BLOCKS, TPB, 0, stream>>>(
        k_cache, v_cache, k_new, v_new, input_pos, out);
}

// Round 8
// 189.443 us; speedup vs baseline: 1.0377x; 1.0377x over previous
//
#include <hip/hip_runtime.h>

// Problem constants (from reference): B=8, H=16, T=16, D=128, S=4096
constexpr int B = 8;
constexpr int H = 16;
constexpr int T = 16;
constexpr int D = 128;
constexpr int S = 4096;
constexpr int D4 = D / 4;                              // float4 per row = 32
constexpr size_t CACHE_ELEMS = (size_t)B * H * S * D;  // 67,108,864 floats
constexpr size_t CACHE_F4    = CACHE_ELEMS / 4;        // 16,777,216 float4

// Native clang vector type — valid for __builtin_nontemporal_{load,store}.
typedef float f4 __attribute__((ext_vector_type(4)));

// Copy tuning: 2048 blocks x 256 threads; each half (k/v) gets 1024 blocks.
// NT on BOTH loads and stores (R7 showed plain loads regress: streams >> LLC,
// allocation is pure eviction churn). UNROLL=8 (R5/R6 A/B best).
// This round: R5 + scatter-operand prefetch hoist only.
constexpr int TPB = 256;
constexpr int COPY_BLOCKS = 2048;
constexpr int BLOCKS_PER_HALF = COPY_BLOCKS / 2;       // 1024
constexpr int UNROLL = 8;
constexpr int ITERS = 8;                                // 8*8 = 64 f4/thread
constexpr int F4_PER_BLOCK = TPB * UNROLL * ITERS;      // 16384 f4 = 512 rows
constexpr int ROWS_PER_BLOCK = F4_PER_BLOCK / D4;       // 512 (within one b,h)
// sanity: 1024 * 16384 = 16,777,216 = CACHE_F4; S/ROWS_PER_BLOCK = 8 blocks/(b,h)

__global__ void __launch_bounds__(TPB)
kv_fused_kernel(const f4* __restrict__ k_cache,
                const f4* __restrict__ v_cache,
                const f4* __restrict__ k_new,
                const f4* __restrict__ v_new,
                const int* __restrict__ input_pos,      // (B, T)
                f4* __restrict__ out) {
    int blk = blockIdx.x;
    const f4* __restrict__ src;
    const f4* __restrict__ newsrc;
    f4* __restrict__ dst;
    if (blk < BLOCKS_PER_HALF) {
        src = k_cache; newsrc = k_new; dst = out;
    } else {
        blk -= BLOCKS_PER_HALF;
        src = v_cache; newsrc = v_new; dst = out + CACHE_F4;
    }

    // ---- Prefetch scatter operands (hide the dependent-load tail) ----
    // Block covers (b,h) = blk/8, s in [s0, s0+512) with s0 = (blk%8)*512.
    int bh = blk >> 3;                // b*H + h
    int b  = bh >> 4;                 // H = 16
    int s0 = (blk & 7) * ROWS_PER_BLOCK;
    int d4 = threadIdx.x & (D4 - 1);  // 0..31
    int tl = threadIdx.x >> 5;        // 0..7
    int  p_pre[T / 8];
    f4   r_pre[T / 8];
#pragma unroll
    for (int tg = 0; tg < T / 8; ++tg) {
        int t = tg * 8 + tl;
        p_pre[tg] = input_pos[b * T + t];
        r_pre[tg] = newsrc[((size_t)bh * T + t) * D4 + d4];
    }

    // ---- Phase 1: bulk copy of this block's 512-row slice (NT both ways) ----
    size_t base = (size_t)blk * F4_PER_BLOCK + threadIdx.x;
    for (int it = 0; it < ITERS; ++it) {
        size_t a = base + (size_t)it * (TPB * UNROLL);
        f4 r[UNROLL];
#pragma unroll
        for (int u = 0; u < UNROLL; ++u)
            r[u] = __builtin_nontemporal_load(&src[a + (size_t)u * TPB]);
#pragma unroll
        for (int u = 0; u < UNROLL; ++u)
            __builtin_nontemporal_store(r[u], &dst[a + (size_t)u * TPB]);
    }

    // ---- Phase 2: overwrite scattered rows that land in this block's slice ----
    __syncthreads();
#pragma unroll
    for (int tg = 0; tg < T / 8; ++tg) {
        int p = p_pre[tg];
        if (p >= s0 && p < s0 + ROWS_PER_BLOCK) {
            dst[((size_t)bh * S + p) * D4 + d4] = r_pre[tg];
        }
    }
}

extern "C" void kernel_launch(void* const* d_in, const int* in_sizes, int n_in,
                              void* d_out, int out_size, void* d_ws, size_t ws_size,
                              hipStream_t stream) {
    // setup_inputs order: input_pos, k, v, k_cache, v_cache
    const int* input_pos = (const int*)d_in[0];
    const f4*  k_new     = (const f4*)d_in[1];
    const f4*  v_new     = (const f4*)d_in[2];
    const f4*  k_cache   = (const f4*)d_in[3];
    const f4*  v_cache   = (const f4*)d_in[4];

    f4* out = (f4*)d_out;

    // Single fused dispatch: copy both caches + in-block scatter overwrite.
    kv_fused_kernel<<<COPY_BLOCKS, TPB, 0, stream>>>(
        k_cache, v_cache, k_new, v_new, input_pos, out);
}